// Round 5
// baseline (248.441 us; speedup 1.0000x reference)
//
#include <hip/hip_runtime.h>
#include <math.h>

// Folded model (exact algebra, per-token):
//   h      = relu(x @ G1 + b11)                      [400 MACs]
//   g      = relu(h @ P1 + x @ P2 + F2)              [800 MACs]
//   logits = g @ M2 + h @ Q1 + x @ Q2 + F3           [180 MACs]
//   out    = softmax(logits)
//
// fwd structure: T=4 tokens/thread; x and h register-resident (x read from
// global exactly ONCE — round 4's mid-kernel HBM re-read was the stall);
// gp computed in two 10-wide halves, each completed into the logits before
// the next (breaks the 252-reg liveness peak that would spill; peak ~225).
// All weight reads are broadcast ds_read_b128 (half-rows padded to 12).

// d_ws float offsets (all 16B-aligned)
#define OFF_G1   0      // [20][20]  G1[k][m], row = 5 b128
#define OFF_P1H  400    // [2][20][12]  P1[k][10*half+j], row = 3 b128
#define OFF_P2H  880    // [2][20][12]  P2[k][10*half+j]
#define OFF_Q1   1360   // [20][4]   {Q1[k][0..2],0}
#define OFF_Q2   1440   // [20][4]
#define OFF_M2   1520   // [20][4]   {M2[m][0..2],0}
#define OFF_B11  1600   // [20]
#define OFF_F2H  1620   // [2][12]   F2[10*half+j] (pad 0)
#define OFF_F3   1644   // [4]
#define NW       1648

// ---- single merged prep kernel (1 block, 512 threads) ----
__global__ void prep_kernel(const float* __restrict__ Wv, const float* __restrict__ Wres,
                            const float* __restrict__ W1, const float* __restrict__ b1,
                            const float* __restrict__ W2, const float* __restrict__ b2,
                            const float* __restrict__ b3, const float* __restrict__ Wc,
                            const float* __restrict__ bc, const float* __restrict__ W3,
                            float* __restrict__ W) {
    __shared__ float G2[400];   // [i][m]  layer-1 (Wv^T+Wres)@W1^T
    __shared__ float M3[60];    // [i][c]  Wc@W3_1
    __shared__ float e1[20];    // b2_0+b3_0
    const int tid = threadIdx.x;

    for (int idx = tid; idx < 480; idx += 512) {
        if (idx < 400) {
            const int i = idx / 20, m = idx % 20;
            float s = 0.f;
            for (int j = 0; j < 20; ++j)
                s = fmaf(Wv[400 + j*20 + i] + Wres[400 + i*20 + j], W1[400 + m*20 + j], s);
            G2[idx] = s;
        } else if (idx < 460) {
            const int r = idx - 400, i = r / 3, c = r % 3;
            float s = 0.f;
            for (int p = 0; p < 20; ++p)
                s = fmaf(Wc[c*20 + p], W3[400 + p*20 + i], s);
            M3[r] = s;
        } else {
            const int j = idx - 460;
            e1[j] = b2[j] + b3[j];
        }
    }
    __syncthreads();

    for (int idx = tid; idx < NW; idx += 512) {
        float s = 0.f;
        if (idx < 400) {                                   // G1[k][m]
            const int k = idx / 20, m = idx % 20;
            for (int j = 0; j < 20; ++j)
                s = fmaf(Wv[j*20 + k] + Wres[k*20 + j], W1[m*20 + j], s);
        } else if (idx < 880) {                            // P1H
            const int r = idx - 400, half = r / 240, rr = r % 240;
            const int k = rr / 12, j = rr % 12, m = 10*half + j;
            if (j < 10)
                for (int i = 0; i < 20; ++i)
                    s = fmaf(W2[i*20 + k], G2[i*20 + m], s);
        } else if (idx < 1360) {                           // P2H
            const int r = idx - 880, half = r / 240, rr = r % 240;
            const int k = rr / 12, j = rr % 12, m = 10*half + j;
            if (j < 10)
                for (int i = 0; i < 20; ++i)
                    s = fmaf(W3[i*20 + k], G2[i*20 + m], s);
        } else if (idx < 1440) {                           // Q1[k][c]
            const int r = idx - 1360, k = r >> 2, c = r & 3;
            if (c < 3)
                for (int i = 0; i < 20; ++i)
                    s = fmaf(W2[i*20 + k], M3[i*3 + c], s);
        } else if (idx < 1520) {                           // Q2[k][c]
            const int r = idx - 1440, k = r >> 2, c = r & 3;
            if (c < 3)
                for (int i = 0; i < 20; ++i)
                    s = fmaf(W3[i*20 + k], M3[i*3 + c], s);
        } else if (idx < 1600) {                           // M2[m][c]
            const int r = idx - 1520, m = r >> 2, c = r & 3;
            if (c < 3)
                for (int p = 0; p < 20; ++p)
                    s = fmaf(Wc[c*20 + p], W2[400 + p*20 + m], s);
        } else if (idx < 1620) {                           // b11
            s = b1[idx - 1600];
        } else if (idx < 1644) {                           // F2H
            const int r = idx - 1620, half = r / 12, j = r % 12;
            const int m = 10*half + j;
            if (j < 10) {
                s = b1[20 + m];
                for (int i = 0; i < 20; ++i)
                    s = fmaf(e1[i], G2[i*20 + m], s);
            }
        } else {                                           // F3
            const int c = idx - 1644;
            if (c < 3) {
                s = bc[c];
                for (int p = 0; p < 20; ++p)
                    s = fmaf(Wc[c*20 + p], b2[20 + p] + b3[20 + p], s);
                for (int i = 0; i < 20; ++i)
                    s = fmaf(e1[i], M3[i*3 + c], s);
            }
        }
        W[idx] = s;
    }
}

__global__ __launch_bounds__(256, 2) void fwd_kernel(const float* __restrict__ X,
                                                     const float* __restrict__ Wg,
                                                     float* __restrict__ out, int nquad) {
    __shared__ float Ws[NW];

    const int q4 = blockIdx.x * 256 + threadIdx.x;   // grid sized exactly: q4 < nquad

    // ---- issue x loads first (20 float4, line-complete: 320 consecutive B) ----
    float x[4][20];
    {
        const float4* xp = reinterpret_cast<const float4*>(X + (size_t)q4 * 80);
        #pragma unroll
        for (int t = 0; t < 4; ++t)
            #pragma unroll
            for (int q = 0; q < 5; ++q) {
                const float4 v = xp[t*5 + q];
                x[t][4*q+0] = v.x; x[t][4*q+1] = v.y;
                x[t][4*q+2] = v.z; x[t][4*q+3] = v.w;
            }
    }
    // ---- stage weights into LDS (overlaps with x loads in flight) ----
    for (int i = threadIdx.x; i < NW; i += 256) Ws[i] = Wg[i];
    __syncthreads();

    const float4* W4 = reinterpret_cast<const float4*>(Ws);

    // ---------- stage 1: h = relu(x @ G1 + b11) ----------
    float h[4][20];
    #pragma unroll
    for (int r = 0; r < 5; ++r) {
        const float4 b = W4[OFF_B11/4 + r];
        #pragma unroll
        for (int t = 0; t < 4; ++t) {
            h[t][4*r+0] = b.x; h[t][4*r+1] = b.y; h[t][4*r+2] = b.z; h[t][4*r+3] = b.w;
        }
    }
    #pragma unroll
    for (int k = 0; k < 20; ++k) {
        #pragma unroll
        for (int r = 0; r < 5; ++r) {
            const float4 w = W4[OFF_G1/4 + k*5 + r];
            #pragma unroll
            for (int t = 0; t < 4; ++t) {
                h[t][4*r+0] = fmaf(x[t][k], w.x, h[t][4*r+0]);
                h[t][4*r+1] = fmaf(x[t][k], w.y, h[t][4*r+1]);
                h[t][4*r+2] = fmaf(x[t][k], w.z, h[t][4*r+2]);
                h[t][4*r+3] = fmaf(x[t][k], w.w, h[t][4*r+3]);
            }
        }
    }
    #pragma unroll
    for (int t = 0; t < 4; ++t)
        #pragma unroll
        for (int i = 0; i < 20; ++i) h[t][i] = fmaxf(h[t][i], 0.f);

    // ---------- logit x/h terms: l = F3 + x @ Q2 + h @ Q1 ----------
    float l[4][3];
    {
        const float4 f3 = W4[OFF_F3/4];
        #pragma unroll
        for (int t = 0; t < 4; ++t) { l[t][0] = f3.x; l[t][1] = f3.y; l[t][2] = f3.z; }
    }
    #pragma unroll
    for (int k = 0; k < 20; ++k) {
        const float4 q2 = W4[OFF_Q2/4 + k];
        const float4 q1 = W4[OFF_Q1/4 + k];
        #pragma unroll
        for (int t = 0; t < 4; ++t) {
            l[t][0] = fmaf(x[t][k], q2.x, l[t][0]);
            l[t][1] = fmaf(x[t][k], q2.y, l[t][1]);
            l[t][2] = fmaf(x[t][k], q2.z, l[t][2]);
            l[t][0] = fmaf(h[t][k], q1.x, l[t][0]);
            l[t][1] = fmaf(h[t][k], q1.y, l[t][1]);
            l[t][2] = fmaf(h[t][k], q1.z, l[t][2]);
        }
    }

    // ---------- gp halves: gph = F2h + x@P2h + h@P1h; l += relu(gph)@M2h ----------
    // Rolled over half (runtime LDS bases only; all register indices are
    // compile-time) — keeps code ~39 KB and liveness peak ~225 VGPRs.
    #pragma unroll 1
    for (int half = 0; half < 2; ++half) {
        const int p1b = OFF_P1H/4 + half*60;
        const int p2b = OFF_P2H/4 + half*60;
        float gph[4][12];
        {
            const float4 f0 = W4[OFF_F2H/4 + half*3 + 0];
            const float4 f1 = W4[OFF_F2H/4 + half*3 + 1];
            const float4 f2 = W4[OFF_F2H/4 + half*3 + 2];
            #pragma unroll
            for (int t = 0; t < 4; ++t) {
                gph[t][0] = f0.x; gph[t][1] = f0.y; gph[t][2]  = f0.z; gph[t][3]  = f0.w;
                gph[t][4] = f1.x; gph[t][5] = f1.y; gph[t][6]  = f1.z; gph[t][7]  = f1.w;
                gph[t][8] = f2.x; gph[t][9] = f2.y; gph[t][10] = f2.z; gph[t][11] = f2.w;
            }
        }
        #pragma unroll
        for (int k = 0; k < 20; ++k) {
            #pragma unroll
            for (int r = 0; r < 3; ++r) {
                const float4 w = W4[p2b + k*3 + r];
                #pragma unroll
                for (int t = 0; t < 4; ++t) {
                    gph[t][4*r+0] = fmaf(x[t][k], w.x, gph[t][4*r+0]);
                    gph[t][4*r+1] = fmaf(x[t][k], w.y, gph[t][4*r+1]);
                    gph[t][4*r+2] = fmaf(x[t][k], w.z, gph[t][4*r+2]);
                    gph[t][4*r+3] = fmaf(x[t][k], w.w, gph[t][4*r+3]);
                }
            }
            #pragma unroll
            for (int r = 0; r < 3; ++r) {
                const float4 w = W4[p1b + k*3 + r];
                #pragma unroll
                for (int t = 0; t < 4; ++t) {
                    gph[t][4*r+0] = fmaf(h[t][k], w.x, gph[t][4*r+0]);
                    gph[t][4*r+1] = fmaf(h[t][k], w.y, gph[t][4*r+1]);
                    gph[t][4*r+2] = fmaf(h[t][k], w.z, gph[t][4*r+2]);
                    gph[t][4*r+3] = fmaf(h[t][k], w.w, gph[t][4*r+3]);
                }
            }
        }
        #pragma unroll
        for (int m = 0; m < 10; ++m) {
            const float4 wm = W4[OFF_M2/4 + half*10 + m];
            #pragma unroll
            for (int t = 0; t < 4; ++t) {
                const float g = fmaxf(gph[t][m], 0.f);
                l[t][0] = fmaf(g, wm.x, l[t][0]);
                l[t][1] = fmaf(g, wm.y, l[t][1]);
                l[t][2] = fmaf(g, wm.z, l[t][2]);
            }
        }
    }

    // ---------- softmax + store (4 tokens × 3 = 3 float4) ----------
    float o[12];
    #pragma unroll
    for (int t = 0; t < 4; ++t) {
        const float m  = fmaxf(fmaxf(l[t][0], l[t][1]), l[t][2]);
        const float e0 = __expf(l[t][0] - m);
        const float e1 = __expf(l[t][1] - m);
        const float e2 = __expf(l[t][2] - m);
        const float r  = 1.f / (e0 + e1 + e2);
        o[3*t+0] = e0 * r; o[3*t+1] = e1 * r; o[3*t+2] = e2 * r;
    }
    float4* o4 = reinterpret_cast<float4*>(out + (size_t)q4 * 12);
    o4[0] = make_float4(o[0], o[1], o[2],  o[3]);
    o4[1] = make_float4(o[4], o[5], o[6],  o[7]);
    o4[2] = make_float4(o[8], o[9], o[10], o[11]);
}

extern "C" void kernel_launch(void* const* d_in, const int* in_sizes, int n_in,
                              void* d_out, int out_size, void* d_ws, size_t ws_size,
                              hipStream_t stream) {
    const float* X    = (const float*)d_in[0];
    // d_in[1]=Wq, d_in[2]=Wk: dead (softmax over singleton axis == 1)
    const float* Wv   = (const float*)d_in[3];
    const float* Wres = (const float*)d_in[4];
    const float* W1   = (const float*)d_in[5];
    const float* b1   = (const float*)d_in[6];
    const float* W2   = (const float*)d_in[7];
    const float* b2   = (const float*)d_in[8];
    const float* W3   = (const float*)d_in[9];
    const float* b3   = (const float*)d_in[10];
    const float* Wc   = (const float*)d_in[11];
    const float* bc   = (const float*)d_in[12];
    float* out = (float*)d_out;
    float* W   = (float*)d_ws;

    const int S = in_sizes[0] / 20;
    const int nquad = S / 4;                    // S = 2^20: exact

    prep_kernel<<<1, 512, 0, stream>>>(Wv, Wres, W1, b1, W2, b2, b3, Wc, bc, W3, W);

    const int grid = nquad / 256;               // exact: 1024 blocks
    fwd_kernel<<<grid, 256, 0, stream>>>(X, W, out, nquad);
}

// Round 6
// 184.677 us; speedup vs baseline: 1.3453x; 1.3453x over previous
//
#include <hip/hip_runtime.h>
#include <math.h>

// Folded model (exact algebra, per-token):
//   h      = relu(x @ G1 + b11)                      [400 MACs]
//   g      = relu(h @ P1 + x @ P2 + F2)              [800 MACs]
//   logits = g @ M2 + h @ Q1 + x @ Q2 + F3           [180 MACs]
//   out    = softmax(logits)
//
// Single fused kernel. Every block redundantly computes the weight folds
// (~150 FMA/thread vs 13 KB of L2-resident raw weights) into its own LDS —
// no prep dispatch, no d_ws dependency.
//
// fwd structure: T=4 tokens/thread, FULLY UNROLLED (rounds 3/5 proved any
// rolled loop with >128 live-through floats triggers memory scratch spills;
// full unroll at ~188 peak apparent liveness schedules into 128 VGPRs with
// zero scratch — round 4). x is consumed chunk-wise in phase 1 by ALL its
// users (h, gp, l) and never re-read (round 4's 87 µs was a mid-kernel HBM
// x re-fetch). All weight reads are broadcast ds_read_b128.

// Ws float offsets
#define OFF_G1   0      // [20][20]  G1[k][m]  (k = x index)
#define OFF_P1   400    // [20][20]  P1[k][m]  (k = h index)
#define OFF_P2   800    // [20][20]  P2[k][m]  (k = x index)
#define OFF_Q1   1200   // [20][4]   {Q1[k][0..2],0}  (k = h index)
#define OFF_Q2   1280   // [20][4]   (k = x index)
#define OFF_M2   1360   // [20][4]   (m = g index)
#define OFF_B11  1440   // [20]
#define OFF_F2   1460   // [20]
#define OFF_F3   1480   // [4]
#define NW       1484

__global__ __launch_bounds__(256, 2) void fused_kernel(
        const float* __restrict__ X,
        const float* __restrict__ Wv, const float* __restrict__ Wres,
        const float* __restrict__ W1, const float* __restrict__ b1,
        const float* __restrict__ W2, const float* __restrict__ b2,
        const float* __restrict__ b3, const float* __restrict__ Wc,
        const float* __restrict__ bc, const float* __restrict__ W3,
        float* __restrict__ out, int nquad) {
    __shared__ float Ws[NW];
    __shared__ float G2[400];   // [i][m]  layer-1 (Wv^T+Wres)@W1^T
    __shared__ float M3[60];    // [i][c]  Wc@W3_1
    __shared__ float e1[20];    // b2_0+b3_0
    const int tid = threadIdx.x;

    // ---- prep phase A: layer-1 folds ----
    for (int idx = tid; idx < 480; idx += 256) {
        if (idx < 400) {
            const int i = idx / 20, m = idx % 20;
            float s = 0.f;
            for (int j = 0; j < 20; ++j)
                s = fmaf(Wv[400 + j*20 + i] + Wres[400 + i*20 + j], W1[400 + m*20 + j], s);
            G2[idx] = s;
        } else if (idx < 460) {
            const int r = idx - 400, i = r / 3, c = r % 3;
            float s = 0.f;
            for (int p = 0; p < 20; ++p)
                s = fmaf(Wc[c*20 + p], W3[400 + p*20 + i], s);
            M3[r] = s;
        } else {
            const int j = idx - 460;
            e1[j] = b2[j] + b3[j];
        }
    }
    __syncthreads();

    // ---- prep phase B: final folded weights into Ws ----
    for (int idx = tid; idx < NW; idx += 256) {
        float s = 0.f;
        if (idx < 400) {                                   // G1[k][m]
            const int k = idx / 20, m = idx % 20;
            for (int j = 0; j < 20; ++j)
                s = fmaf(Wv[j*20 + k] + Wres[k*20 + j], W1[m*20 + j], s);
        } else if (idx < 800) {                            // P1[k][m]
            const int r = idx - 400, k = r / 20, m = r % 20;
            for (int i = 0; i < 20; ++i)
                s = fmaf(W2[i*20 + k], G2[i*20 + m], s);
        } else if (idx < 1200) {                           // P2[k][m]
            const int r = idx - 800, k = r / 20, m = r % 20;
            for (int i = 0; i < 20; ++i)
                s = fmaf(W3[i*20 + k], G2[i*20 + m], s);
        } else if (idx < 1280) {                           // Q1[k][c]
            const int r = idx - 1200, k = r >> 2, c = r & 3;
            if (c < 3)
                for (int i = 0; i < 20; ++i)
                    s = fmaf(W2[i*20 + k], M3[i*3 + c], s);
        } else if (idx < 1360) {                           // Q2[k][c]
            const int r = idx - 1280, k = r >> 2, c = r & 3;
            if (c < 3)
                for (int i = 0; i < 20; ++i)
                    s = fmaf(W3[i*20 + k], M3[i*3 + c], s);
        } else if (idx < 1440) {                           // M2[m][c]
            const int r = idx - 1360, m = r >> 2, c = r & 3;
            if (c < 3)
                for (int p = 0; p < 20; ++p)
                    s = fmaf(Wc[c*20 + p], W2[400 + p*20 + m], s);
        } else if (idx < 1460) {                           // b11
            s = b1[idx - 1440];
        } else if (idx < 1480) {                           // F2[m]
            const int m = idx - 1460;
            s = b1[20 + m];
            for (int i = 0; i < 20; ++i)
                s = fmaf(e1[i], G2[i*20 + m], s);
        } else {                                           // F3[c]
            const int c = idx - 1480;
            if (c < 3) {
                s = bc[c];
                for (int p = 0; p < 20; ++p)
                    s = fmaf(Wc[c*20 + p], b2[20 + p] + b3[20 + p], s);
                for (int i = 0; i < 20; ++i)
                    s = fmaf(e1[i], M3[i*3 + c], s);
            }
        }
        Ws[idx] = s;
    }
    __syncthreads();

    const float4* W4 = reinterpret_cast<const float4*>(Ws);
    const int q4 = blockIdx.x * 256 + tid;            // grid exact: q4 < nquad
    const float* xbase = X + (size_t)q4 * 80;         // 4 tokens x 20 floats

    // ---- init accumulators ----
    float h[4][20], gp[4][20], l[4][3];
    #pragma unroll
    for (int r = 0; r < 5; ++r) {
        const float4 b = W4[OFF_B11/4 + r];
        const float4 f = W4[OFF_F2/4 + r];
        #pragma unroll
        for (int t = 0; t < 4; ++t) {
            h[t][4*r+0]  = b.x; h[t][4*r+1]  = b.y; h[t][4*r+2]  = b.z; h[t][4*r+3]  = b.w;
            gp[t][4*r+0] = f.x; gp[t][4*r+1] = f.y; gp[t][4*r+2] = f.z; gp[t][4*r+3] = f.w;
        }
    }
    {
        const float4 f3 = W4[OFF_F3/4];
        #pragma unroll
        for (int t = 0; t < 4; ++t) { l[t][0] = f3.x; l[t][1] = f3.y; l[t][2] = f3.z; }
    }

    // ---- phase 1: stream x once; h += x@G1, gp += x@P2, l += x@Q2 ----
    #pragma unroll
    for (int q = 0; q < 5; ++q) {
        float xr[4][4];
        #pragma unroll
        for (int t = 0; t < 4; ++t) {
            const float4 v = *reinterpret_cast<const float4*>(xbase + t*20 + q*4);
            xr[t][0] = v.x; xr[t][1] = v.y; xr[t][2] = v.z; xr[t][3] = v.w;
        }
        #pragma unroll
        for (int kk = 0; kk < 4; ++kk) {
            const int k = q*4 + kk;                   // compile-time
            #pragma unroll
            for (int r = 0; r < 5; ++r) {
                const float4 w = W4[OFF_G1/4 + k*5 + r];
                #pragma unroll
                for (int t = 0; t < 4; ++t) {
                    h[t][4*r+0] = fmaf(xr[t][kk], w.x, h[t][4*r+0]);
                    h[t][4*r+1] = fmaf(xr[t][kk], w.y, h[t][4*r+1]);
                    h[t][4*r+2] = fmaf(xr[t][kk], w.z, h[t][4*r+2]);
                    h[t][4*r+3] = fmaf(xr[t][kk], w.w, h[t][4*r+3]);
                }
            }
            #pragma unroll
            for (int r = 0; r < 5; ++r) {
                const float4 w = W4[OFF_P2/4 + k*5 + r];
                #pragma unroll
                for (int t = 0; t < 4; ++t) {
                    gp[t][4*r+0] = fmaf(xr[t][kk], w.x, gp[t][4*r+0]);
                    gp[t][4*r+1] = fmaf(xr[t][kk], w.y, gp[t][4*r+1]);
                    gp[t][4*r+2] = fmaf(xr[t][kk], w.z, gp[t][4*r+2]);
                    gp[t][4*r+3] = fmaf(xr[t][kk], w.w, gp[t][4*r+3]);
                }
            }
            {
                const float4 wq = W4[OFF_Q2/4 + k];
                #pragma unroll
                for (int t = 0; t < 4; ++t) {
                    l[t][0] = fmaf(xr[t][kk], wq.x, l[t][0]);
                    l[t][1] = fmaf(xr[t][kk], wq.y, l[t][1]);
                    l[t][2] = fmaf(xr[t][kk], wq.z, l[t][2]);
                }
            }
        }
    }

    // ---- relu h ----
    #pragma unroll
    for (int t = 0; t < 4; ++t)
        #pragma unroll
        for (int i = 0; i < 20; ++i) h[t][i] = fmaxf(h[t][i], 0.f);

    // ---- phase 2: gp += h@P1, l += h@Q1 (h dies progressively) ----
    #pragma unroll
    for (int k = 0; k < 20; ++k) {
        #pragma unroll
        for (int r = 0; r < 5; ++r) {
            const float4 w = W4[OFF_P1/4 + k*5 + r];
            #pragma unroll
            for (int t = 0; t < 4; ++t) {
                gp[t][4*r+0] = fmaf(h[t][k], w.x, gp[t][4*r+0]);
                gp[t][4*r+1] = fmaf(h[t][k], w.y, gp[t][4*r+1]);
                gp[t][4*r+2] = fmaf(h[t][k], w.z, gp[t][4*r+2]);
                gp[t][4*r+3] = fmaf(h[t][k], w.w, gp[t][4*r+3]);
            }
        }
        const float4 wq = W4[OFF_Q1/4 + k];
        #pragma unroll
        for (int t = 0; t < 4; ++t) {
            l[t][0] = fmaf(h[t][k], wq.x, l[t][0]);
            l[t][1] = fmaf(h[t][k], wq.y, l[t][1]);
            l[t][2] = fmaf(h[t][k], wq.z, l[t][2]);
        }
    }

    // ---- phase 3: g = relu(gp); l += g@M2 ----
    #pragma unroll
    for (int m = 0; m < 20; ++m) {
        const float4 wm = W4[OFF_M2/4 + m];
        #pragma unroll
        for (int t = 0; t < 4; ++t) {
            const float g = fmaxf(gp[t][m], 0.f);
            l[t][0] = fmaf(g, wm.x, l[t][0]);
            l[t][1] = fmaf(g, wm.y, l[t][1]);
            l[t][2] = fmaf(g, wm.z, l[t][2]);
        }
    }

    // ---- softmax + store (4 tokens x 3 = 3 float4) ----
    float o[12];
    #pragma unroll
    for (int t = 0; t < 4; ++t) {
        const float m  = fmaxf(fmaxf(l[t][0], l[t][1]), l[t][2]);
        const float e0 = __expf(l[t][0] - m);
        const float e1 = __expf(l[t][1] - m);
        const float e2 = __expf(l[t][2] - m);
        const float r  = 1.f / (e0 + e1 + e2);
        o[3*t+0] = e0 * r; o[3*t+1] = e1 * r; o[3*t+2] = e2 * r;
    }
    float4* o4 = reinterpret_cast<float4*>(out + (size_t)q4 * 12);
    o4[0] = make_float4(o[0], o[1], o[2],  o[3]);
    o4[1] = make_float4(o[4], o[5], o[6],  o[7]);
    o4[2] = make_float4(o[8], o[9], o[10], o[11]);
}

extern "C" void kernel_launch(void* const* d_in, const int* in_sizes, int n_in,
                              void* d_out, int out_size, void* d_ws, size_t ws_size,
                              hipStream_t stream) {
    const float* X    = (const float*)d_in[0];
    // d_in[1]=Wq, d_in[2]=Wk: dead (softmax over singleton axis == 1)
    const float* Wv   = (const float*)d_in[3];
    const float* Wres = (const float*)d_in[4];
    const float* W1   = (const float*)d_in[5];
    const float* b1   = (const float*)d_in[6];
    const float* W2   = (const float*)d_in[7];
    const float* b2   = (const float*)d_in[8];
    const float* W3   = (const float*)d_in[9];
    const float* b3   = (const float*)d_in[10];
    const float* Wc   = (const float*)d_in[11];
    const float* bc   = (const float*)d_in[12];
    float* out = (float*)d_out;

    const int S = in_sizes[0] / 20;
    const int nquad = S / 4;                    // S = 2^20: exact
    const int grid = nquad / 256;               // exact: 1024 blocks

    fused_kernel<<<grid, 256, 0, stream>>>(X, Wv, Wres, W1, b1, W2, b2, b3,
                                           Wc, bc, W3, out, nquad);
}